// Round 5
// baseline (164.767 us; speedup 1.0000x reference)
//
#include <hip/hip_runtime.h>
#include <math.h>

#define NVARS 14
#define EDIM 32
#define VMIX 3
#define KSTATES 16384
#define BATCH 32

// bf16 swizzled-fragment regions in ws (byte offsets):
#define WS_DSWZ_B  32768                       // [V][18][64][8] bf16 = 55296 B
#define WS_W2SWZ_B (WS_DSWZ_B + 55296)         // [V][9][26][64][8] = 718848 B
#define WS_W3SWZ_B (WS_W2SWZ_B + 718848)       // [V][13][4][64][8] = 79872 B

// LDS strides (shorts). H1S: 148dw%32=20 -> 2-way b128 (free).
// H2S: 420 shorts = 210dw, 210%32=18 -> 2-way b128 (free); 64*420*2=53760B
// keeps total block LDS <= 54613 so 3 blocks/CU fit (single grid round).
#define H1S 296
#define H2S 420
#define MS  72

typedef __attribute__((ext_vector_type(8))) short bf16x8;
typedef __attribute__((ext_vector_type(4))) float f32x4;

static __device__ inline unsigned short f2bf(float f) {
    unsigned u = __float_as_uint(f);
    u += 0x7FFFu + ((u >> 16) & 1u);   // RNE
    return (unsigned short)(u >> 16);
}
static __device__ inline float elu(float x) {
    return x > 0.f ? x : (__expf(x) - 1.f);
}

// ---------------- pre (single kernel, role-split grid) ----------------
// blocks [0,172): W2eff/W3eff fragment swizzles (54912 groups)
// blocks [172,214): Dmat delta rows k<14 (block = (v,k)); recomputes its T cols
// blocks [214,217): Dmat base row k=14 + zero-fill k>=15 (block = v)
__global__ __launch_bounds__(320) void pre_kernel(const float* __restrict__ emb,
                                                  const float* __restrict__ lin_w,
                                                  const float* __restrict__ lin_b,
                                                  const float* __restrict__ b1,
                                                  const float* __restrict__ w1,
                                                  const float* __restrict__ w2,
                                                  const float* __restrict__ w3,
                                                  float* __restrict__ ws) {
    int blk = blockIdx.x;
    int tid = threadIdx.x;
    char* wsb = (char*)ws;
    unsigned short* dmat = (unsigned short*)(wsb + WS_DSWZ_B);
    __shared__ float sP[128];
    __shared__ float sQ[64];

    if (blk < 172) {
        int g2 = blk * 320 + tid;
        if (g2 >= 54912) return;
        bf16x8 o8;
        if (g2 < 44928) {                  // W2eff
            int h = g2;
            int v = h / 14976;
            int r = h % 14976;
            int kt = r / 1664;
            int r2 = r % 1664;
            int nt = r2 / 64, l = r2 % 64;
            int n = nt * 16 + (l & 15);
            int kbase = kt * 32 + ((l >> 4) & 3) * 8;
            #pragma unroll
            for (int j = 0; j < 8; ++j) {
                int k = kbase + j;         // k < 288
                float val = 0.f;
                if (n < 400) {
                    int i = k / 9, p = k % 9;
                    int py = p / 3, px = p % 3;
                    int o = n / 25, q = n % 25;
                    int qy = q / 5, qx = q % 5;
                    int ty = qy - py, tx = qx - px;
                    if (ty >= 0 && ty < 3 && tx >= 0 && tx < 3)
                        val = w2[((size_t)(v * 32 + i) * 16 + o) * 9 + ty * 3 + tx];
                }
                o8[j] = (short)f2bf(val);
            }
        } else {                           // W3eff
            int h = g2 - 44928;
            int v = h / 3328;
            int r = h % 3328;
            int kt = r / 256;
            int r2 = r % 256;
            int nt = r2 / 64, l = r2 % 64;
            int n = nt * 16 + (l & 15);    // output pixel 0..48 (else pad)
            int kbase = kt * 32 + ((l >> 4) & 3) * 8;
            #pragma unroll
            for (int j = 0; j < 8; ++j) {
                int k = kbase + j;
                float val = 0.f;
                if (k < 400 && n < 49) {
                    int o = k / 25, q = k % 25;
                    int qy = q / 5, qx = q % 5;
                    int py = n / 7, px = n % 7;
                    int ty = py - qy, tx = px - qx;
                    if (ty >= 0 && ty < 3 && tx >= 0 && tx < 3)
                        val = w3[(size_t)(v * 16 + o) * 9 + ty * 3 + tx];
                }
                o8[j] = (short)f2bf(val);
            }
        }
        *(bf16x8*)(wsb + WS_DSWZ_B + ((size_t)g2 + 3456) * 16) = o8;
        return;
    }

    if (blk < 214) {                       // delta row (v,k)
        int b = blk - 172;
        int v = b / 14;
        int k = b % 14;
        if (tid < 128) {                   // T columns: sP[c*64+i]
            int c = tid >> 6, i = tid & 63;
            const float* e = emb + (k * 2 + c) * EDIM;
            const float* lw = lin_w + ((size_t)v * 448 + k * 32) * 64 + i;
            float a0 = 0.f, a1 = 0.f;
            #pragma unroll
            for (int e2 = 0; e2 < 32; e2 += 2) {
                a0 = fmaf(e[e2], lw[e2 * 64], a0);
                a1 = fmaf(e[e2 + 1], lw[(e2 + 1) * 64], a1);
            }
            sP[tid] = a0 + a1;
        }
        __syncthreads();
        if (tid < 64) sQ[tid] = sP[64 + tid] - sP[tid];
        __syncthreads();
        if (tid < 288) {
            int n = tid;
            const float* w1v = w1 + (size_t)v * 64 * 288 + n;
            float a0 = 0.f, a1 = 0.f;
            #pragma unroll
            for (int i = 0; i < 64; i += 2) {
                a0 = fmaf(sQ[i], w1v[i * 288], a0);
                a1 = fmaf(sQ[i + 1], w1v[(i + 1) * 288], a1);
            }
            int nt = n >> 4;
            int l = (n & 15) | ((k >> 3) << 4);
            dmat[((size_t)(v * 18 + nt) * 64 + l) * 8 + (k & 7)] = f2bf(a0 + a1);
        }
        return;
    }

    {                                      // base row + zero-fill, block = v
        int v = blk - 214;
        // zero all k>=15 slots of this v's Dmat region
        for (int t = tid; t < 9216; t += 320) {
            int j3 = t & 7;
            int l = (t >> 3) & 63;
            int k2 = ((l >> 4) << 3) | j3;
            if (k2 >= 15) dmat[(size_t)v * 9216 + t] = 0;
        }
        if (tid < 128) {                   // partial sums of c=0 T columns
            int half = tid >> 6, i = tid & 63;
            float a0 = 0.f, a1 = 0.f;
            for (int n2 = half * 7; n2 < half * 7 + 7; ++n2) {
                const float* e = emb + (n2 * 2) * EDIM;
                const float* lw = lin_w + ((size_t)v * 448 + n2 * 32) * 64 + i;
                #pragma unroll
                for (int e2 = 0; e2 < 32; e2 += 2) {
                    a0 = fmaf(e[e2], lw[e2 * 64], a0);
                    a1 = fmaf(e[e2 + 1], lw[(e2 + 1) * 64], a1);
                }
            }
            sP[tid] = a0 + a1;
        }
        __syncthreads();
        if (tid < 64) sQ[tid] = lin_b[v * 64 + tid] + sP[tid] + sP[64 + tid];
        __syncthreads();
        if (tid < 288) {
            int n = tid;
            const float* w1v = w1 + (size_t)v * 64 * 288 + n;
            float a0 = b1[v * 32 + n / 9], a1 = 0.f;
            #pragma unroll
            for (int i = 0; i < 64; i += 2) {
                a0 = fmaf(sQ[i], w1v[i * 288], a0);
                a1 = fmaf(sQ[i + 1], w1v[(i + 1) * 288], a1);
            }
            int nt = n >> 4;
            int l = (n & 15) | 16;         // k=14 -> quadK 1, j 6
            dmat[((size_t)(v * 18 + nt) * 64 + l) * 8 + 6] = f2bf(a0 + a1);
        }
    }
}

// ---------------- main: MFMA decoder + distance (512 threads, 8 waves) ----------------
__global__ __launch_bounds__(512, 6) void emission_main(const float* __restrict__ x,
                                                        const float* __restrict__ b2,
                                                        const float* __restrict__ b3p,
                                                        const float* __restrict__ ws,
                                                        float* __restrict__ out) {
    int bid = blockIdx.x;
    // XCD swizzle: v-trio for a chunk shares bid%8 and is temporally close.
    int group = bid / 24;
    int j24 = bid % 24;
    int v = j24 >> 3;
    int chunk = group * 8 + (j24 & 7);    // states [chunk*64, chunk*64+64)
    int tid = threadIdx.x;
    int w = tid >> 6;           // wave 0..7
    int l = tid & 63;
    int quad = l >> 4;
    int lc = l & 15;
    const char* wsb = (const char*)ws;

    // union: sH1 (64 x H1S shorts) -> sH2 (64 x H2S) -> sM (64 x MS)
    __shared__ __align__(16) unsigned short uni[64 * H2S];
    __shared__ float sMsq[64];
    __shared__ float sXsq[32];
    __shared__ float sB2[16];

    // ---------- P0: small LDS prep ----------
    if (tid < 16) sB2[tid] = b2[v * 16 + tid];
    if (tid < 64) sMsq[tid] = 0.f;
    if (tid >= 64 && tid < 96) {
        int b = tid - 64;
        const float* xb = x + (size_t)(b * 3 + v) * 49;
        float s = 0.f;
        #pragma unroll
        for (int p = 0; p < 49; ++p) s = fmaf(xb[p], xb[p], s);
        sXsq[b] = s;
    }

    int mt0 = w & 3;            // this wave's m-tile for P0b/P3
    // ---------- P0b: H1 = ELU(bits @ Dmat); wave (mt0, nh = w>>2) ----------
    {
        int nh = w >> 2;
        int sg = chunk * 64 + mt0 * 16 + lc;
        bf16x8 abits;
        #pragma unroll
        for (int j = 0; j < 8; ++j) {
            int k = quad * 8 + j;
            unsigned short u = 0;
            if (k < 14) u = ((sg >> (13 - k)) & 1) ? 0x3F80 : 0;
            else if (k == 14) u = 0x3F80;
            abits[j] = (short)u;
        }
        const bf16x8* dsw = (const bf16x8*)(wsb + WS_DSWZ_B) + (size_t)v * 18 * 64;
        for (int i = 0; i < 9; ++i) {
            int nt = nh * 9 + i;
            bf16x8 bfrag = dsw[nt * 64 + l];
            f32x4 d = {0.f, 0.f, 0.f, 0.f};
            d = __builtin_amdgcn_mfma_f32_16x16x32_bf16(abits, bfrag, d, 0, 0, 0);
            #pragma unroll
            for (int r = 0; r < 4; ++r)
                uni[(mt0 * 16 + quad * 4 + r) * H1S + nt * 16 + lc] = f2bf(elu(d[r]));
        }
    }
    __syncthreads();

    // ---------- P1: conv2 GEMM  H2pre(64x416) = H1(64x288) @ W2eff ----------
    int ncnt = (w < 2) ? 4 : 3;
    int n0 = (w < 2) ? 4 * w : 8 + 3 * (w - 2);   // 26 n-tiles over 8 waves
    f32x4 acc[4][4];
    #pragma unroll
    for (int mt = 0; mt < 4; ++mt)
        #pragma unroll
        for (int j = 0; j < 4; ++j)
            acc[mt][j] = (f32x4){0.f, 0.f, 0.f, 0.f};
    {
        const bf16x8* w2f = (const bf16x8*)(wsb + WS_W2SWZ_B) + (size_t)v * 9 * 26 * 64;
        for (int kt = 0; kt < 9; ++kt) {
            bf16x8 a[4];
            #pragma unroll
            for (int mt = 0; mt < 4; ++mt)
                a[mt] = *(const bf16x8*)&uni[(mt * 16 + lc) * H1S + kt * 32 + quad * 8];
            bf16x8 bfr[4];
            #pragma unroll
            for (int j = 0; j < 4; ++j)
                if (j < ncnt) bfr[j] = w2f[(kt * 26 + n0 + j) * 64 + l];
            #pragma unroll
            for (int j = 0; j < 4; ++j)
                if (j < ncnt)
                    #pragma unroll
                    for (int mt = 0; mt < 4; ++mt)
                        acc[mt][j] = __builtin_amdgcn_mfma_f32_16x16x32_bf16(a[mt], bfr[j], acc[mt][j], 0, 0, 0);
        }
    }
    __syncthreads();   // all H1 reads done before uni is reused as sH2

    // X A-frags for P4 (this wave's b-tile bt = w>>2), built in registers
    bf16x8 xf[2];
    {
        int bt = w >> 2;
        #pragma unroll
        for (int kt = 0; kt < 2; ++kt) {
            int b = bt * 16 + lc;
            #pragma unroll
            for (int j = 0; j < 8; ++j) {
                int p = kt * 32 + quad * 8 + j;
                unsigned short u = 0;
                if (p < 49) u = f2bf(x[(size_t)(b * 3 + v) * 49 + p]);
                xf[kt][j] = (short)u;
            }
        }
    }

    // ---------- P2: bias + ELU + bf16 -> sH2[s][H2S] ----------
    #pragma unroll
    for (int j = 0; j < 4; ++j) {
        if (j < ncnt) {
            int n = (n0 + j) * 16 + lc;
            #pragma unroll
            for (int mt = 0; mt < 4; ++mt) {
                #pragma unroll
                for (int r = 0; r < 4; ++r) {
                    float val = 0.f;
                    if (n < 400) {
                        int o = n / 25;
                        val = elu(acc[mt][j][r] + sB2[o]);
                    }
                    uni[(mt * 16 + quad * 4 + r) * H2S + n] = f2bf(val);
                }
            }
        }
    }
    __syncthreads();

    // ---------- P3: conv3 GEMM  m(64x64) = H2(64x416) @ W3eff ----------
    // wave: (mt0 = w&3, p-tiles {ph, ph+2}, ph = w>>2)
    int ph = w >> 2;
    f32x4 acc2[2];
    acc2[0] = (f32x4){0.f, 0.f, 0.f, 0.f};
    acc2[1] = (f32x4){0.f, 0.f, 0.f, 0.f};
    {
        const bf16x8* w3f = (const bf16x8*)(wsb + WS_W3SWZ_B) + (size_t)v * 13 * 4 * 64;
        for (int kt = 0; kt < 13; ++kt) {
            bf16x8 a = *(const bf16x8*)&uni[(mt0 * 16 + lc) * H2S + kt * 32 + quad * 8];
            #pragma unroll
            for (int c = 0; c < 2; ++c) {
                int pt = ph + 2 * c;
                bf16x8 bfr = w3f[(kt * 4 + pt) * 64 + l];
                acc2[c] = __builtin_amdgcn_mfma_f32_16x16x32_bf16(a, bfr, acc2[c], 0, 0, 0);
            }
        }
    }
    // epilogue: means, ||m||^2
    float b3v = b3p[v];
    float mv[2][4];
    #pragma unroll
    for (int c = 0; c < 2; ++c) {
        int p = (ph + 2 * c) * 16 + lc;
        #pragma unroll
        for (int r = 0; r < 4; ++r)
            mv[c][r] = (p < 49) ? (acc2[c][r] + b3v) : 0.f;
    }
    #pragma unroll
    for (int r = 0; r < 4; ++r) {
        float sq = mv[0][r] * mv[0][r] + mv[1][r] * mv[1][r];
        sq += __shfl_xor(sq, 1, 64);
        sq += __shfl_xor(sq, 2, 64);
        sq += __shfl_xor(sq, 4, 64);
        sq += __shfl_xor(sq, 8, 64);
        if (lc == 0) atomicAdd(&sMsq[mt0 * 16 + quad * 4 + r], sq);
    }
    __syncthreads();   // conv3 reads of uni done before reuse as sM
    #pragma unroll
    for (int c = 0; c < 2; ++c) {
        int p = (ph + 2 * c) * 16 + lc;
        #pragma unroll
        for (int r = 0; r < 4; ++r)
            uni[(mt0 * 16 + quad * 4 + r) * MS + p] = f2bf(mv[c][r]);
    }
    __syncthreads();

    // ---------- P4: cross = X(32x64p) @ M^T, wave: (st = w&3, bt = w>>2) ----------
    {
        int st = w & 3, bt = w >> 2;
        f32x4 acc3 = {0.f, 0.f, 0.f, 0.f};
        #pragma unroll
        for (int kt = 0; kt < 2; ++kt) {
            bf16x8 bm = *(const bf16x8*)&uni[(st * 16 + lc) * MS + kt * 32 + quad * 8];
            acc3 = __builtin_amdgcn_mfma_f32_16x16x32_bf16(xf[kt], bm, acc3, 0, 0, 0);
        }
        int s = st * 16 + lc;
        float msq = sMsq[s];
        size_t kidx = (size_t)(chunk * 64 + s) * 3 + v;
        #pragma unroll
        for (int r = 0; r < 4; ++r) {
            int b = bt * 16 + quad * 4 + r;
            out[(size_t)b * (KSTATES * 3) + kidx] = acc3[r] - 0.5f * (msq + sXsq[b]);
        }
    }
}

extern "C" void kernel_launch(void* const* d_in, const int* in_sizes, int n_in,
                              void* d_out, int out_size, void* d_ws, size_t ws_size,
                              hipStream_t stream) {
    const float* x    = (const float*)d_in[0];   // (32,3,7,7)
    const float* emb  = (const float*)d_in[1];   // (14,2,32)
    const float* linw = (const float*)d_in[2];   // (3,448,64)
    const float* linb = (const float*)d_in[3];   // (3,64)
    const float* w1   = (const float*)d_in[4];   // (3,64,32,3,3)
    const float* b1   = (const float*)d_in[5];   // (3,32)
    const float* w2   = (const float*)d_in[6];   // (3,32,16,3,3)
    const float* b2   = (const float*)d_in[7];   // (3,16)
    const float* w3   = (const float*)d_in[8];   // (3,16,1,3,3)
    const float* b3   = (const float*)d_in[9];   // (3,1)
    float* out = (float*)d_out;
    float* ws = (float*)d_ws;

    pre_kernel<<<217, 320, 0, stream>>>(emb, linw, linb, b1, w1, w2, w3, ws);
    emission_main<<<768, 512, 0, stream>>>(x, b2, b3, ws, out);
}

// Round 6
// 110.617 us; speedup vs baseline: 1.4895x; 1.4895x over previous
//
#include <hip/hip_runtime.h>
#include <math.h>

#define NVARS 14
#define EDIM 32
#define VMIX 3
#define KSTATES 16384
#define BATCH 32

// bf16 swizzled-fragment regions in ws (byte offsets):
#define WS_DSWZ_B  32768                       // [V][18][64][8] bf16 = 55296 B
#define WS_W2SWZ_B (WS_DSWZ_B + 55296)         // [V][9][26][64][8] = 718848 B
#define WS_W3SWZ_B (WS_W2SWZ_B + 718848)       // [V][13][4][64][8] = 79872 B

// LDS strides (shorts). H1S: 148dw%32=20 -> 2-way b128 (free).
// H2S: 420 shorts = 210dw, 210%32=18 -> 2-way b128 (free); 64*420*2=53760B
// keeps total block LDS <= 54613 so 3 blocks/CU fit (single grid round).
// NOTE: do NOT raise __launch_bounds__ min-waves beyond 4 — (512,6) forced
// VGPR=40 and spilled (R5: WRITE_SIZE 24->83MB, main 33->95us).
#define H1S 296
#define H2S 420
#define MS  72

typedef __attribute__((ext_vector_type(8))) short bf16x8;
typedef __attribute__((ext_vector_type(4))) float f32x4;

static __device__ inline unsigned short f2bf(float f) {
    unsigned u = __float_as_uint(f);
    u += 0x7FFFu + ((u >> 16) & 1u);   // RNE
    return (unsigned short)(u >> 16);
}
static __device__ inline float elu(float x) {
    return x > 0.f ? x : (__expf(x) - 1.f);
}

// ---------------- pre (single kernel, role-split grid) ----------------
// blocks [0,172): W2eff/W3eff fragment swizzles (54912 groups)
// blocks [172,214): Dmat delta rows k<14 (block = (v,k)); recomputes its T cols
// blocks [214,217): Dmat base row k=14 + zero-fill k>=15 (block = v)
__global__ __launch_bounds__(320) void pre_kernel(const float* __restrict__ emb,
                                                  const float* __restrict__ lin_w,
                                                  const float* __restrict__ lin_b,
                                                  const float* __restrict__ b1,
                                                  const float* __restrict__ w1,
                                                  const float* __restrict__ w2,
                                                  const float* __restrict__ w3,
                                                  float* __restrict__ ws) {
    int blk = blockIdx.x;
    int tid = threadIdx.x;
    char* wsb = (char*)ws;
    unsigned short* dmat = (unsigned short*)(wsb + WS_DSWZ_B);
    __shared__ float sP[128];
    __shared__ float sQ[64];

    if (blk < 172) {
        int g2 = blk * 320 + tid;
        if (g2 >= 54912) return;
        bf16x8 o8;
        if (g2 < 44928) {                  // W2eff
            int h = g2;
            int v = h / 14976;
            int r = h % 14976;
            int kt = r / 1664;
            int r2 = r % 1664;
            int nt = r2 / 64, l = r2 % 64;
            int n = nt * 16 + (l & 15);
            int kbase = kt * 32 + ((l >> 4) & 3) * 8;
            #pragma unroll
            for (int j = 0; j < 8; ++j) {
                int k = kbase + j;         // k < 288
                float val = 0.f;
                if (n < 400) {
                    int i = k / 9, p = k % 9;
                    int py = p / 3, px = p % 3;
                    int o = n / 25, q = n % 25;
                    int qy = q / 5, qx = q % 5;
                    int ty = qy - py, tx = qx - px;
                    if (ty >= 0 && ty < 3 && tx >= 0 && tx < 3)
                        val = w2[((size_t)(v * 32 + i) * 16 + o) * 9 + ty * 3 + tx];
                }
                o8[j] = (short)f2bf(val);
            }
        } else {                           // W3eff
            int h = g2 - 44928;
            int v = h / 3328;
            int r = h % 3328;
            int kt = r / 256;
            int r2 = r % 256;
            int nt = r2 / 64, l = r2 % 64;
            int n = nt * 16 + (l & 15);    // output pixel 0..48 (else pad)
            int kbase = kt * 32 + ((l >> 4) & 3) * 8;
            #pragma unroll
            for (int j = 0; j < 8; ++j) {
                int k = kbase + j;
                float val = 0.f;
                if (k < 400 && n < 49) {
                    int o = k / 25, q = k % 25;
                    int qy = q / 5, qx = q % 5;
                    int py = n / 7, px = n % 7;
                    int ty = py - qy, tx = px - qx;
                    if (ty >= 0 && ty < 3 && tx >= 0 && tx < 3)
                        val = w3[(size_t)(v * 16 + o) * 9 + ty * 3 + tx];
                }
                o8[j] = (short)f2bf(val);
            }
        }
        *(bf16x8*)(wsb + WS_DSWZ_B + ((size_t)g2 + 3456) * 16) = o8;
        return;
    }

    if (blk < 214) {                       // delta row (v,k)
        int b = blk - 172;
        int v = b / 14;
        int k = b % 14;
        if (tid < 128) {                   // T columns: sP[c*64+i]
            int c = tid >> 6, i = tid & 63;
            const float* e = emb + (k * 2 + c) * EDIM;
            const float* lw = lin_w + ((size_t)v * 448 + k * 32) * 64 + i;
            float a0 = 0.f, a1 = 0.f;
            #pragma unroll
            for (int e2 = 0; e2 < 32; e2 += 2) {
                a0 = fmaf(e[e2], lw[e2 * 64], a0);
                a1 = fmaf(e[e2 + 1], lw[(e2 + 1) * 64], a1);
            }
            sP[tid] = a0 + a1;
        }
        __syncthreads();
        if (tid < 64) sQ[tid] = sP[64 + tid] - sP[tid];
        __syncthreads();
        if (tid < 288) {
            int n = tid;
            const float* w1v = w1 + (size_t)v * 64 * 288 + n;
            float a0 = 0.f, a1 = 0.f;
            #pragma unroll
            for (int i = 0; i < 64; i += 2) {
                a0 = fmaf(sQ[i], w1v[i * 288], a0);
                a1 = fmaf(sQ[i + 1], w1v[(i + 1) * 288], a1);
            }
            int nt = n >> 4;
            int l = (n & 15) | ((k >> 3) << 4);
            dmat[((size_t)(v * 18 + nt) * 64 + l) * 8 + (k & 7)] = f2bf(a0 + a1);
        }
        return;
    }

    {                                      // base row + zero-fill, block = v
        int v = blk - 214;
        // zero all k>=15 slots of this v's Dmat region
        for (int t = tid; t < 9216; t += 320) {
            int j3 = t & 7;
            int l = (t >> 3) & 63;
            int k2 = ((l >> 4) << 3) | j3;
            if (k2 >= 15) dmat[(size_t)v * 9216 + t] = 0;
        }
        if (tid < 128) {                   // partial sums of c=0 T columns
            int half = tid >> 6, i = tid & 63;
            float a0 = 0.f, a1 = 0.f;
            for (int n2 = half * 7; n2 < half * 7 + 7; ++n2) {
                const float* e = emb + (n2 * 2) * EDIM;
                const float* lw = lin_w + ((size_t)v * 448 + n2 * 32) * 64 + i;
                #pragma unroll
                for (int e2 = 0; e2 < 32; e2 += 2) {
                    a0 = fmaf(e[e2], lw[e2 * 64], a0);
                    a1 = fmaf(e[e2 + 1], lw[(e2 + 1) * 64], a1);
                }
            }
            sP[tid] = a0 + a1;
        }
        __syncthreads();
        if (tid < 64) sQ[tid] = lin_b[v * 64 + tid] + sP[tid] + sP[64 + tid];
        __syncthreads();
        if (tid < 288) {
            int n = tid;
            const float* w1v = w1 + (size_t)v * 64 * 288 + n;
            float a0 = b1[v * 32 + n / 9], a1 = 0.f;
            #pragma unroll
            for (int i = 0; i < 64; i += 2) {
                a0 = fmaf(sQ[i], w1v[i * 288], a0);
                a1 = fmaf(sQ[i + 1], w1v[(i + 1) * 288], a1);
            }
            int nt = n >> 4;
            int l = (n & 15) | 16;         // k=14 -> quadK 1, j 6
            dmat[((size_t)(v * 18 + nt) * 64 + l) * 8 + 6] = f2bf(a0 + a1);
        }
    }
}

// ---------------- main: MFMA decoder + distance (512 threads, 8 waves) ----------------
__global__ __launch_bounds__(512, 4) void emission_main(const float* __restrict__ x,
                                                        const float* __restrict__ b2,
                                                        const float* __restrict__ b3p,
                                                        const float* __restrict__ ws,
                                                        float* __restrict__ out) {
    int bid = blockIdx.x;
    // XCD swizzle: v-trio for a chunk shares bid%8 and is temporally close.
    int group = bid / 24;
    int j24 = bid % 24;
    int v = j24 >> 3;
    int chunk = group * 8 + (j24 & 7);    // states [chunk*64, chunk*64+64)
    int tid = threadIdx.x;
    int w = tid >> 6;           // wave 0..7
    int l = tid & 63;
    int quad = l >> 4;
    int lc = l & 15;
    const char* wsb = (const char*)ws;

    // union: sH1 (64 x H1S shorts) -> sH2 (64 x H2S) -> sM (64 x MS)
    __shared__ __align__(16) unsigned short uni[64 * H2S];
    __shared__ float sMsq[64];
    __shared__ float sXsq[32];
    __shared__ float sB2[16];

    // ---------- P0: small LDS prep ----------
    if (tid < 16) sB2[tid] = b2[v * 16 + tid];
    if (tid < 64) sMsq[tid] = 0.f;
    if (tid >= 64 && tid < 96) {
        int b = tid - 64;
        const float* xb = x + (size_t)(b * 3 + v) * 49;
        float s = 0.f;
        #pragma unroll
        for (int p = 0; p < 49; ++p) s = fmaf(xb[p], xb[p], s);
        sXsq[b] = s;
    }

    int mt0 = w & 3;            // this wave's m-tile for P0b/P3
    // ---------- P0b: H1 = ELU(bits @ Dmat); wave (mt0, nh = w>>2) ----------
    {
        int nh = w >> 2;
        int sg = chunk * 64 + mt0 * 16 + lc;
        bf16x8 abits;
        #pragma unroll
        for (int j = 0; j < 8; ++j) {
            int k = quad * 8 + j;
            unsigned short u = 0;
            if (k < 14) u = ((sg >> (13 - k)) & 1) ? 0x3F80 : 0;
            else if (k == 14) u = 0x3F80;
            abits[j] = (short)u;
        }
        const bf16x8* dsw = (const bf16x8*)(wsb + WS_DSWZ_B) + (size_t)v * 18 * 64;
        for (int i = 0; i < 9; ++i) {
            int nt = nh * 9 + i;
            bf16x8 bfrag = dsw[nt * 64 + l];
            f32x4 d = {0.f, 0.f, 0.f, 0.f};
            d = __builtin_amdgcn_mfma_f32_16x16x32_bf16(abits, bfrag, d, 0, 0, 0);
            #pragma unroll
            for (int r = 0; r < 4; ++r)
                uni[(mt0 * 16 + quad * 4 + r) * H1S + nt * 16 + lc] = f2bf(elu(d[r]));
        }
    }
    __syncthreads();

    // ---------- P1: conv2 GEMM  H2pre(64x416) = H1(64x288) @ W2eff ----------
    int ncnt = (w < 2) ? 4 : 3;
    int n0 = (w < 2) ? 4 * w : 8 + 3 * (w - 2);   // 26 n-tiles over 8 waves
    f32x4 acc[4][4];
    #pragma unroll
    for (int mt = 0; mt < 4; ++mt)
        #pragma unroll
        for (int j = 0; j < 4; ++j)
            acc[mt][j] = (f32x4){0.f, 0.f, 0.f, 0.f};
    {
        const bf16x8* w2f = (const bf16x8*)(wsb + WS_W2SWZ_B) + (size_t)v * 9 * 26 * 64;
        for (int kt = 0; kt < 9; ++kt) {
            bf16x8 a[4];
            #pragma unroll
            for (int mt = 0; mt < 4; ++mt)
                a[mt] = *(const bf16x8*)&uni[(mt * 16 + lc) * H1S + kt * 32 + quad * 8];
            bf16x8 bfr[4];
            #pragma unroll
            for (int j = 0; j < 4; ++j)
                if (j < ncnt) bfr[j] = w2f[(kt * 26 + n0 + j) * 64 + l];
            #pragma unroll
            for (int j = 0; j < 4; ++j)
                if (j < ncnt)
                    #pragma unroll
                    for (int mt = 0; mt < 4; ++mt)
                        acc[mt][j] = __builtin_amdgcn_mfma_f32_16x16x32_bf16(a[mt], bfr[j], acc[mt][j], 0, 0, 0);
        }
    }
    __syncthreads();   // all H1 reads done before uni is reused as sH2

    // X A-frags for P4 (this wave's b-tile bt = w>>2), built in registers
    bf16x8 xf[2];
    {
        int bt = w >> 2;
        #pragma unroll
        for (int kt = 0; kt < 2; ++kt) {
            int b = bt * 16 + lc;
            #pragma unroll
            for (int j = 0; j < 8; ++j) {
                int p = kt * 32 + quad * 8 + j;
                unsigned short u = 0;
                if (p < 49) u = f2bf(x[(size_t)(b * 3 + v) * 49 + p]);
                xf[kt][j] = (short)u;
            }
        }
    }

    // ---------- P2: bias + ELU + bf16 -> sH2[s][H2S] ----------
    #pragma unroll
    for (int j = 0; j < 4; ++j) {
        if (j < ncnt) {
            int n = (n0 + j) * 16 + lc;
            #pragma unroll
            for (int mt = 0; mt < 4; ++mt) {
                #pragma unroll
                for (int r = 0; r < 4; ++r) {
                    float val = 0.f;
                    if (n < 400) {
                        int o = n / 25;
                        val = elu(acc[mt][j][r] + sB2[o]);
                    }
                    uni[(mt * 16 + quad * 4 + r) * H2S + n] = f2bf(val);
                }
            }
        }
    }
    __syncthreads();

    // ---------- P3: conv3 GEMM  m(64x64) = H2(64x416) @ W3eff ----------
    // wave: (mt0 = w&3, p-tiles {ph, ph+2}, ph = w>>2)
    int ph = w >> 2;
    f32x4 acc2[2];
    acc2[0] = (f32x4){0.f, 0.f, 0.f, 0.f};
    acc2[1] = (f32x4){0.f, 0.f, 0.f, 0.f};
    {
        const bf16x8* w3f = (const bf16x8*)(wsb + WS_W3SWZ_B) + (size_t)v * 13 * 4 * 64;
        for (int kt = 0; kt < 13; ++kt) {
            bf16x8 a = *(const bf16x8*)&uni[(mt0 * 16 + lc) * H2S + kt * 32 + quad * 8];
            #pragma unroll
            for (int c = 0; c < 2; ++c) {
                int pt = ph + 2 * c;
                bf16x8 bfr = w3f[(kt * 4 + pt) * 64 + l];
                acc2[c] = __builtin_amdgcn_mfma_f32_16x16x32_bf16(a, bfr, acc2[c], 0, 0, 0);
            }
        }
    }
    // epilogue: means, ||m||^2
    float b3v = b3p[v];
    float mv[2][4];
    #pragma unroll
    for (int c = 0; c < 2; ++c) {
        int p = (ph + 2 * c) * 16 + lc;
        #pragma unroll
        for (int r = 0; r < 4; ++r)
            mv[c][r] = (p < 49) ? (acc2[c][r] + b3v) : 0.f;
    }
    #pragma unroll
    for (int r = 0; r < 4; ++r) {
        float sq = mv[0][r] * mv[0][r] + mv[1][r] * mv[1][r];
        sq += __shfl_xor(sq, 1, 64);
        sq += __shfl_xor(sq, 2, 64);
        sq += __shfl_xor(sq, 4, 64);
        sq += __shfl_xor(sq, 8, 64);
        if (lc == 0) atomicAdd(&sMsq[mt0 * 16 + quad * 4 + r], sq);
    }
    __syncthreads();   // conv3 reads of uni done before reuse as sM
    #pragma unroll
    for (int c = 0; c < 2; ++c) {
        int p = (ph + 2 * c) * 16 + lc;
        #pragma unroll
        for (int r = 0; r < 4; ++r)
            uni[(mt0 * 16 + quad * 4 + r) * MS + p] = f2bf(mv[c][r]);
    }
    __syncthreads();

    // ---------- P4: cross = X(32x64p) @ M^T, wave: (st = w&3, bt = w>>2) ----------
    {
        int st = w & 3, bt = w >> 2;
        f32x4 acc3 = {0.f, 0.f, 0.f, 0.f};
        #pragma unroll
        for (int kt = 0; kt < 2; ++kt) {
            bf16x8 bm = *(const bf16x8*)&uni[(st * 16 + lc) * MS + kt * 32 + quad * 8];
            acc3 = __builtin_amdgcn_mfma_f32_16x16x32_bf16(xf[kt], bm, acc3, 0, 0, 0);
        }
        int s = st * 16 + lc;
        float msq = sMsq[s];
        size_t kidx = (size_t)(chunk * 64 + s) * 3 + v;
        #pragma unroll
        for (int r = 0; r < 4; ++r) {
            int b = bt * 16 + quad * 4 + r;
            out[(size_t)b * (KSTATES * 3) + kidx] = acc3[r] - 0.5f * (msq + sXsq[b]);
        }
    }
}

extern "C" void kernel_launch(void* const* d_in, const int* in_sizes, int n_in,
                              void* d_out, int out_size, void* d_ws, size_t ws_size,
                              hipStream_t stream) {
    const float* x    = (const float*)d_in[0];   // (32,3,7,7)
    const float* emb  = (const float*)d_in[1];   // (14,2,32)
    const float* linw = (const float*)d_in[2];   // (3,448,64)
    const float* linb = (const float*)d_in[3];   // (3,64)
    const float* w1   = (const float*)d_in[4];   // (3,64,32,3,3)
    const float* b1   = (const float*)d_in[5];   // (3,32)
    const float* w2   = (const float*)d_in[6];   // (3,32,16,3,3)
    const float* b2   = (const float*)d_in[7];   // (3,16)
    const float* w3   = (const float*)d_in[8];   // (3,16,1,3,3)
    const float* b3   = (const float*)d_in[9];   // (3,1)
    float* out = (float*)d_out;
    float* ws = (float*)d_ws;

    pre_kernel<<<217, 320, 0, stream>>>(emb, linw, linb, b1, w1, w2, w3, ws);
    emission_main<<<768, 512, 0, stream>>>(x, b2, b3, ws, out);
}

// Round 7
// 109.683 us; speedup vs baseline: 1.5022x; 1.0085x over previous
//
#include <hip/hip_runtime.h>
#include <math.h>

#define NVARS 14
#define EDIM 32
#define VMIX 3
#define KSTATES 16384
#define BATCH 32

// bf16 swizzled-fragment regions in ws (byte offsets):
#define WS_DSWZ_B  32768                       // [V][18][64][8] bf16 = 55296 B
#define WS_W2SWZ_B (WS_DSWZ_B + 55296)         // [V][9][26][64][8] = 718848 B
#define WS_W3SWZ_B (WS_W2SWZ_B + 718848)       // [V][13][4][64][8] = 79872 B

// LDS strides (shorts). H1S: 148dw%32=20 -> 2-way b128 (free).
// H2S: 420 shorts = 210dw, 210%32=18 -> 2-way b128 (free); 64*420*2=53760B
// keeps total block LDS <= 54613 so 3 blocks/CU fit (single grid round).
// NOTE: do NOT raise __launch_bounds__ min-waves beyond 4 — (512,6) forced
// VGPR=40 and spilled (R5: WRITE_SIZE 24->83MB, main 33->95us).
#define H1S 296
#define H2S 420
#define MS  72

typedef __attribute__((ext_vector_type(8))) short bf16x8;
typedef __attribute__((ext_vector_type(4))) float f32x4;

static __device__ inline unsigned short f2bf(float f) {
    unsigned u = __float_as_uint(f);
    u += 0x7FFFu + ((u >> 16) & 1u);   // RNE
    return (unsigned short)(u >> 16);
}
static __device__ inline float elu(float x) {
    return x > 0.f ? x : (__expf(x) - 1.f);
}

// ---------------- pre (single kernel, role-split grid) ----------------
// blocks [0,172): W2eff/W3eff fragment swizzles (54912 groups)
// blocks [172,214): Dmat delta rows k<14 (block = (v,k)); recomputes its T cols
// blocks [214,217): Dmat base row k=14 + zero-fill k>=15 (block = v)
__global__ __launch_bounds__(320) void pre_kernel(const float* __restrict__ emb,
                                                  const float* __restrict__ lin_w,
                                                  const float* __restrict__ lin_b,
                                                  const float* __restrict__ b1,
                                                  const float* __restrict__ w1,
                                                  const float* __restrict__ w2,
                                                  const float* __restrict__ w3,
                                                  float* __restrict__ ws) {
    int blk = blockIdx.x;
    int tid = threadIdx.x;
    char* wsb = (char*)ws;
    unsigned short* dmat = (unsigned short*)(wsb + WS_DSWZ_B);
    __shared__ float sP[128];
    __shared__ float sQ[64];

    if (blk < 172) {
        int g2 = blk * 320 + tid;
        if (g2 >= 54912) return;
        bf16x8 o8;
        if (g2 < 44928) {                  // W2eff
            int h = g2;
            int v = h / 14976;
            int r = h % 14976;
            int kt = r / 1664;
            int r2 = r % 1664;
            int nt = r2 / 64, l = r2 % 64;
            int n = nt * 16 + (l & 15);
            int kbase = kt * 32 + ((l >> 4) & 3) * 8;
            #pragma unroll
            for (int j = 0; j < 8; ++j) {
                int k = kbase + j;         // k < 288
                float val = 0.f;
                if (n < 400) {
                    int i = k / 9, p = k % 9;
                    int py = p / 3, px = p % 3;
                    int o = n / 25, q = n % 25;
                    int qy = q / 5, qx = q % 5;
                    int ty = qy - py, tx = qx - px;
                    if (ty >= 0 && ty < 3 && tx >= 0 && tx < 3)
                        val = w2[((size_t)(v * 32 + i) * 16 + o) * 9 + ty * 3 + tx];
                }
                o8[j] = (short)f2bf(val);
            }
        } else {                           // W3eff
            int h = g2 - 44928;
            int v = h / 3328;
            int r = h % 3328;
            int kt = r / 256;
            int r2 = r % 256;
            int nt = r2 / 64, l = r2 % 64;
            int n = nt * 16 + (l & 15);    // output pixel 0..48 (else pad)
            int kbase = kt * 32 + ((l >> 4) & 3) * 8;
            #pragma unroll
            for (int j = 0; j < 8; ++j) {
                int k = kbase + j;
                float val = 0.f;
                if (k < 400 && n < 49) {
                    int o = k / 25, q = k % 25;
                    int qy = q / 5, qx = q % 5;
                    int py = n / 7, px = n % 7;
                    int ty = py - qy, tx = px - qx;
                    if (ty >= 0 && ty < 3 && tx >= 0 && tx < 3)
                        val = w3[(size_t)(v * 16 + o) * 9 + ty * 3 + tx];
                }
                o8[j] = (short)f2bf(val);
            }
        }
        *(bf16x8*)(wsb + WS_DSWZ_B + ((size_t)g2 + 3456) * 16) = o8;
        return;
    }

    if (blk < 214) {                       // delta row (v,k)
        int b = blk - 172;
        int v = b / 14;
        int k = b % 14;
        if (tid < 128) {                   // T columns: sP[c*64+i]
            int c = tid >> 6, i = tid & 63;
            const float* e = emb + (k * 2 + c) * EDIM;
            const float* lw = lin_w + ((size_t)v * 448 + k * 32) * 64 + i;
            float a0 = 0.f, a1 = 0.f;
            #pragma unroll
            for (int e2 = 0; e2 < 32; e2 += 2) {
                a0 = fmaf(e[e2], lw[e2 * 64], a0);
                a1 = fmaf(e[e2 + 1], lw[(e2 + 1) * 64], a1);
            }
            sP[tid] = a0 + a1;
        }
        __syncthreads();
        if (tid < 64) sQ[tid] = sP[64 + tid] - sP[tid];
        __syncthreads();
        if (tid < 288) {
            int n = tid;
            const float* w1v = w1 + (size_t)v * 64 * 288 + n;
            float a0 = 0.f, a1 = 0.f;
            #pragma unroll
            for (int i = 0; i < 64; i += 2) {
                a0 = fmaf(sQ[i], w1v[i * 288], a0);
                a1 = fmaf(sQ[i + 1], w1v[(i + 1) * 288], a1);
            }
            int nt = n >> 4;
            int l = (n & 15) | ((k >> 3) << 4);
            dmat[((size_t)(v * 18 + nt) * 64 + l) * 8 + (k & 7)] = f2bf(a0 + a1);
        }
        return;
    }

    {                                      // base row + zero-fill, block = v
        int v = blk - 214;
        // zero all k>=15 slots of this v's Dmat region
        for (int t = tid; t < 9216; t += 320) {
            int j3 = t & 7;
            int l = (t >> 3) & 63;
            int k2 = ((l >> 4) << 3) | j3;
            if (k2 >= 15) dmat[(size_t)v * 9216 + t] = 0;
        }
        if (tid < 128) {                   // partial sums of c=0 T columns
            int half = tid >> 6, i = tid & 63;
            float a0 = 0.f, a1 = 0.f;
            for (int n2 = half * 7; n2 < half * 7 + 7; ++n2) {
                const float* e = emb + (n2 * 2) * EDIM;
                const float* lw = lin_w + ((size_t)v * 448 + n2 * 32) * 64 + i;
                #pragma unroll
                for (int e2 = 0; e2 < 32; e2 += 2) {
                    a0 = fmaf(e[e2], lw[e2 * 64], a0);
                    a1 = fmaf(e[e2 + 1], lw[(e2 + 1) * 64], a1);
                }
            }
            sP[tid] = a0 + a1;
        }
        __syncthreads();
        if (tid < 64) sQ[tid] = lin_b[v * 64 + tid] + sP[tid] + sP[64 + tid];
        __syncthreads();
        if (tid < 288) {
            int n = tid;
            const float* w1v = w1 + (size_t)v * 64 * 288 + n;
            float a0 = b1[v * 32 + n / 9], a1 = 0.f;
            #pragma unroll
            for (int i = 0; i < 64; i += 2) {
                a0 = fmaf(sQ[i], w1v[i * 288], a0);
                a1 = fmaf(sQ[i + 1], w1v[(i + 1) * 288], a1);
            }
            int nt = n >> 4;
            int l = (n & 15) | 16;         // k=14 -> quadK 1, j 6
            dmat[((size_t)(v * 18 + nt) * 64 + l) * 8 + 6] = f2bf(a0 + a1);
        }
    }
}

// ---------------- main: MFMA decoder + distance (512 threads, 8 waves) ----------------
__global__ __launch_bounds__(512, 4) void emission_main(const float* __restrict__ x,
                                                        const float* __restrict__ b2,
                                                        const float* __restrict__ b3p,
                                                        const float* __restrict__ ws,
                                                        float* __restrict__ out) {
    int bid = blockIdx.x;
    // XCD swizzle: v-trio for a chunk shares bid%8 and is temporally close.
    int group = bid / 24;
    int j24 = bid % 24;
    int v = j24 >> 3;
    int chunk = group * 8 + (j24 & 7);    // states [chunk*64, chunk*64+64)
    int tid = threadIdx.x;
    int w = tid >> 6;           // wave 0..7
    int l = tid & 63;
    int quad = l >> 4;
    int lc = l & 15;
    const char* wsb = (const char*)ws;

    // union: sH1 (64 x H1S shorts) -> sH2 (64 x H2S) -> sM (64 x MS)
    __shared__ __align__(16) unsigned short uni[64 * H2S];
    __shared__ float sMsq[64];
    __shared__ float sXsq[32];
    __shared__ float sB2[16];

    // ---------- P0: small LDS prep ----------
    if (tid < 16) sB2[tid] = b2[v * 16 + tid];
    if (tid < 64) sMsq[tid] = 0.f;
    if (tid >= 64 && tid < 96) {
        int b = tid - 64;
        const float* xb = x + (size_t)(b * 3 + v) * 49;
        float s = 0.f;
        #pragma unroll
        for (int p = 0; p < 49; ++p) s = fmaf(xb[p], xb[p], s);
        sXsq[b] = s;
    }

    int mt0 = w & 3;            // this wave's m-tile for P0b/P3
    // ---------- P0b: H1 = ELU(bits @ Dmat); wave (mt0, nh = w>>2) ----------
    {
        int nh = w >> 2;
        int sg = chunk * 64 + mt0 * 16 + lc;
        bf16x8 abits;
        #pragma unroll
        for (int j = 0; j < 8; ++j) {
            int k = quad * 8 + j;
            unsigned short u = 0;
            if (k < 14) u = ((sg >> (13 - k)) & 1) ? 0x3F80 : 0;
            else if (k == 14) u = 0x3F80;
            abits[j] = (short)u;
        }
        const bf16x8* dsw = (const bf16x8*)(wsb + WS_DSWZ_B) + (size_t)v * 18 * 64;
        for (int i = 0; i < 9; ++i) {
            int nt = nh * 9 + i;
            bf16x8 bfrag = dsw[nt * 64 + l];
            f32x4 d = {0.f, 0.f, 0.f, 0.f};
            d = __builtin_amdgcn_mfma_f32_16x16x32_bf16(abits, bfrag, d, 0, 0, 0);
            #pragma unroll
            for (int r = 0; r < 4; ++r)
                uni[(mt0 * 16 + quad * 4 + r) * H1S + nt * 16 + lc] = f2bf(elu(d[r]));
        }
    }
    __syncthreads();

    // ---------- P1: conv2 GEMM  H2pre(64x400) = H1(64x288) @ W2eff ----------
    // n-tile 25 (cols 400-415) is identically zero -> skipped; 25 real tiles:
    // wave 0 gets {0..3}, wave w>=1 gets {1+3w .. 3+3w} (max 24).
    int ncnt = (w == 0) ? 4 : 3;
    int n0 = (w == 0) ? 0 : 1 + 3 * w;
    f32x4 acc[4][4];
    #pragma unroll
    for (int mt = 0; mt < 4; ++mt)
        #pragma unroll
        for (int j = 0; j < 4; ++j)
            acc[mt][j] = (f32x4){0.f, 0.f, 0.f, 0.f};
    {
        const bf16x8* w2f = (const bf16x8*)(wsb + WS_W2SWZ_B) + (size_t)v * 9 * 26 * 64;
        for (int kt = 0; kt < 9; ++kt) {
            bf16x8 a[4];
            #pragma unroll
            for (int mt = 0; mt < 4; ++mt)
                a[mt] = *(const bf16x8*)&uni[(mt * 16 + lc) * H1S + kt * 32 + quad * 8];
            bf16x8 bfr[4];
            #pragma unroll
            for (int j = 0; j < 4; ++j)
                if (j < ncnt) bfr[j] = w2f[(kt * 26 + n0 + j) * 64 + l];
            #pragma unroll
            for (int j = 0; j < 4; ++j)
                if (j < ncnt)
                    #pragma unroll
                    for (int mt = 0; mt < 4; ++mt)
                        acc[mt][j] = __builtin_amdgcn_mfma_f32_16x16x32_bf16(a[mt], bfr[j], acc[mt][j], 0, 0, 0);
        }
    }
    __syncthreads();   // all H1 reads done before uni is reused as sH2

    // X A-frags for P4 (this wave's b-tile bt = w>>2), built in registers
    bf16x8 xf[2];
    {
        int bt = w >> 2;
        #pragma unroll
        for (int kt = 0; kt < 2; ++kt) {
            int b = bt * 16 + lc;
            #pragma unroll
            for (int j = 0; j < 8; ++j) {
                int p = kt * 32 + quad * 8 + j;
                unsigned short u = 0;
                if (p < 49) u = f2bf(x[(size_t)(b * 3 + v) * 49 + p]);
                xf[kt][j] = (short)u;
            }
        }
    }

    // ---------- P2: bias + ELU + bf16 -> sH2[s][H2S] ----------
    #pragma unroll
    for (int j = 0; j < 4; ++j) {
        if (j < ncnt) {
            int n = (n0 + j) * 16 + lc;
            #pragma unroll
            for (int mt = 0; mt < 4; ++mt) {
                #pragma unroll
                for (int r = 0; r < 4; ++r) {
                    float val = 0.f;
                    if (n < 400) {
                        int o = n / 25;
                        val = elu(acc[mt][j][r] + sB2[o]);
                    }
                    uni[(mt * 16 + quad * 4 + r) * H2S + n] = f2bf(val);
                }
            }
        }
    }
    // wave 1: store-only zero tile 25 (cols 400..415) so P3's A is clean
    if (w == 1) {
        for (int s4 = quad; s4 < 64; s4 += 4)
            uni[s4 * H2S + 400 + lc] = 0;
    }
    __syncthreads();

    // ---------- P3: conv3 GEMM  m(64x64) = H2(64x416) @ W3eff ----------
    // wave: (mt0 = w&3, p-tiles {ph, ph+2}, ph = w>>2)
    int ph = w >> 2;
    f32x4 acc2[2];
    acc2[0] = (f32x4){0.f, 0.f, 0.f, 0.f};
    acc2[1] = (f32x4){0.f, 0.f, 0.f, 0.f};
    {
        const bf16x8* w3f = (const bf16x8*)(wsb + WS_W3SWZ_B) + (size_t)v * 13 * 4 * 64;
        for (int kt = 0; kt < 13; ++kt) {
            bf16x8 a = *(const bf16x8*)&uni[(mt0 * 16 + lc) * H2S + kt * 32 + quad * 8];
            #pragma unroll
            for (int c = 0; c < 2; ++c) {
                int pt = ph + 2 * c;
                bf16x8 bfr = w3f[(kt * 4 + pt) * 64 + l];
                acc2[c] = __builtin_amdgcn_mfma_f32_16x16x32_bf16(a, bfr, acc2[c], 0, 0, 0);
            }
        }
    }
    // epilogue: means, ||m||^2
    float b3v = b3p[v];
    float mv[2][4];
    #pragma unroll
    for (int c = 0; c < 2; ++c) {
        int p = (ph + 2 * c) * 16 + lc;
        #pragma unroll
        for (int r = 0; r < 4; ++r)
            mv[c][r] = (p < 49) ? (acc2[c][r] + b3v) : 0.f;
    }
    #pragma unroll
    for (int r = 0; r < 4; ++r) {
        float sq = mv[0][r] * mv[0][r] + mv[1][r] * mv[1][r];
        sq += __shfl_xor(sq, 1, 64);
        sq += __shfl_xor(sq, 2, 64);
        sq += __shfl_xor(sq, 4, 64);
        sq += __shfl_xor(sq, 8, 64);
        if (lc == 0) atomicAdd(&sMsq[mt0 * 16 + quad * 4 + r], sq);
    }
    __syncthreads();   // conv3 reads of uni done before reuse as sM
    #pragma unroll
    for (int c = 0; c < 2; ++c) {
        int p = (ph + 2 * c) * 16 + lc;
        #pragma unroll
        for (int r = 0; r < 4; ++r)
            uni[(mt0 * 16 + quad * 4 + r) * MS + p] = f2bf(mv[c][r]);
    }
    __syncthreads();

    // ---------- P4: cross = X(32x64p) @ M^T, wave: (st = w&3, bt = w>>2) ----------
    {
        int st = w & 3, bt = w >> 2;
        f32x4 acc3 = {0.f, 0.f, 0.f, 0.f};
        #pragma unroll
        for (int kt = 0; kt < 2; ++kt) {
            bf16x8 bm = *(const bf16x8*)&uni[(st * 16 + lc) * MS + kt * 32 + quad * 8];
            acc3 = __builtin_amdgcn_mfma_f32_16x16x32_bf16(xf[kt], bm, acc3, 0, 0, 0);
        }
        int s = st * 16 + lc;
        float msq = sMsq[s];
        size_t kidx = (size_t)(chunk * 64 + s) * 3 + v;
        #pragma unroll
        for (int r = 0; r < 4; ++r) {
            int b = bt * 16 + quad * 4 + r;
            out[(size_t)b * (KSTATES * 3) + kidx] = acc3[r] - 0.5f * (msq + sXsq[b]);
        }
    }
}

extern "C" void kernel_launch(void* const* d_in, const int* in_sizes, int n_in,
                              void* d_out, int out_size, void* d_ws, size_t ws_size,
                              hipStream_t stream) {
    const float* x    = (const float*)d_in[0];   // (32,3,7,7)
    const float* emb  = (const float*)d_in[1];   // (14,2,32)
    const float* linw = (const float*)d_in[2];   // (3,448,64)
    const float* linb = (const float*)d_in[3];   // (3,64)
    const float* w1   = (const float*)d_in[4];   // (3,64,32,3,3)
    const float* b1   = (const float*)d_in[5];   // (3,32)
    const float* w2   = (const float*)d_in[6];   // (3,32,16,3,3)
    const float* b2   = (const float*)d_in[7];   // (3,16)
    const float* w3   = (const float*)d_in[8];   // (3,16,1,3,3)
    const float* b3   = (const float*)d_in[9];   // (3,1)
    float* out = (float*)d_out;
    float* ws = (float*)d_ws;

    pre_kernel<<<217, 320, 0, stream>>>(emb, linw, linb, b1, w1, w2, w3, ws);
    emission_main<<<768, 512, 0, stream>>>(x, b2, b3, ws, out);
}